// Round 6
// baseline (368.358 us; speedup 1.0000x reference)
//
#include <hip/hip_runtime.h>
#include <math.h>

#define IN_F   50
#define HID    256
#define OUT_F  121
#define N_LAYERS 4
#define K0PAD  64

typedef __attribute__((ext_vector_type(8))) short short8;
typedef __attribute__((ext_vector_type(4))) float f32x4;

#define GLOBAL_AS __attribute__((address_space(1)))
#define LDS_AS    __attribute__((address_space(3)))

__device__ __forceinline__ ushort f2bf(float f) {
    union { float f; unsigned u; } c; c.f = f;
    unsigned u = c.u;
    u += 0x7fffu + ((u >> 16) & 1u);
    return (ushort)(u >> 16);
}
__device__ __forceinline__ float bf2f(ushort u) {
    union { unsigned u; float f; } c; c.u = ((unsigned)u) << 16;
    return c.f;
}

// ---------------- prep: all weight converts + counts zero, one kernel ----------------
__global__ __launch_bounds__(256) void prep_kernel(
        const float* __restrict__ x, const float* __restrict__ w0,
        const float* __restrict__ W, const float* __restrict__ w1,
        ushort* __restrict__ x_bf, ushort* __restrict__ wt0,
        ushort* __restrict__ Wt, ushort* __restrict__ wt1,
        int* __restrict__ counts, int n) {
    long long flat = (long long)blockIdx.x * 256 + threadIdx.x;
    long long r0 = (long long)n * K0PAD;
    if (flat < r0) {                       // x -> x_bf padded to K=64
        int nd = (int)(flat >> 6), k = (int)(flat & 63);
        x_bf[flat] = (k < IN_F) ? f2bf(x[(size_t)nd * IN_F + k]) : 0;
        return;
    }
    flat -= r0;
    if (flat < HID * K0PAD) {              // lin0_w transpose
        int nn = (int)(flat >> 6), k = (int)(flat & 63);
        wt0[flat] = (k < IN_F) ? f2bf(w0[(size_t)k * HID + nn]) : 0;
        return;
    }
    flat -= HID * K0PAD;
    if (flat < N_LAYERS * HID * HID) {     // W fold beta + transpose
        int l = (int)(flat >> 16);
        int rem = (int)(flat & 65535);
        int nn = rem >> 8, k = rem & 255;
        float beta = logf(0.5f / (float)(l + 1) + 1.0f);
        float v = beta * W[(size_t)l * HID * HID + (size_t)k * HID + nn];
        if (k == nn) v += 1.0f - beta;
        Wt[flat] = f2bf(v);
        return;
    }
    flat -= N_LAYERS * HID * HID;
    if (flat < 128 * HID) {                // lin1_w transpose, pad 121->128
        int nn = (int)(flat >> 8), k = (int)(flat & 255);
        wt1[flat] = (nn < OUT_F) ? f2bf(w1[(size_t)k * OUT_F + nn]) : 0;
        return;
    }
    flat -= 128 * HID;
    if (flat < n) counts[flat] = 0;
}

// ---------------- CSR build ----------------
__global__ void hist_kernel(const int* __restrict__ dst, int* __restrict__ counts, int E) {
    int e = blockIdx.x * blockDim.x + threadIdx.x;
    if (e < E) atomicAdd(&counts[dst[e]], 1);
}

__global__ void scan_phase1(const int* __restrict__ counts, int* __restrict__ row_ptr,
                            int* __restrict__ bsum, int n) {
    __shared__ int sd[1024];
    int t = threadIdx.x;
    int i = blockIdx.x * 1024 + t;
    int v = (i < n) ? counts[i] : 0;
    sd[t] = v;
    __syncthreads();
    for (int off = 1; off < 1024; off <<= 1) {
        int tmp = (t >= off) ? sd[t - off] : 0;
        __syncthreads();
        sd[t] += tmp;
        __syncthreads();
    }
    if (i < n) row_ptr[i] = sd[t] - v;
    if (t == 1023) bsum[blockIdx.x] = sd[1023];
}

__global__ void scan_phase2(int* __restrict__ bsum, int nb) {
    __shared__ int sd[64];
    int t = threadIdx.x;
    int v = (t < nb) ? bsum[t] : 0;
    sd[t] = v;
    __syncthreads();
    for (int off = 1; off < 64; off <<= 1) {
        int tmp = (t >= off) ? sd[t - off] : 0;
        __syncthreads();
        sd[t] += tmp;
        __syncthreads();
    }
    if (t < nb) bsum[t] = sd[t] - v;
    if (t == nb - 1) bsum[nb] = sd[t];
}

__global__ void scan_phase3(int* __restrict__ row_ptr, int* __restrict__ cursor,
                            const int* __restrict__ bsum, int n, int nb) {
    int i = blockIdx.x * 1024 + threadIdx.x;
    if (i < n) {
        int v = row_ptr[i] + bsum[blockIdx.x];
        row_ptr[i] = v;
        cursor[i]  = v;
    }
    if (i == n - 1) row_ptr[n] = bsum[nb];
}

__global__ void scatter_kernel(const int* __restrict__ src, const int* __restrict__ dst,
                               const float* __restrict__ ew, int* __restrict__ cursor,
                               int* __restrict__ col, float* __restrict__ wv, int E) {
    int e = blockIdx.x * blockDim.x + threadIdx.x;
    if (e < E) {
        int d = dst[e];
        int pos = atomicAdd(&cursor[d], 1);
        col[pos] = src[e];
        wv[pos] = ew[e];
    }
}

// ---------------- lin0 MFMA: x0 = relu(x_bf @ Wt0^T + b), K=64 ----------------
__global__ __launch_bounds__(256) void lin0_mfma(
        const ushort* __restrict__ x_bf, const ushort* __restrict__ wt0,
        const float* __restrict__ b, ushort* __restrict__ x0_bf,
        ushort* __restrict__ h_bf, int M) {
    __shared__ ushort As[4][128][8];
    __shared__ ushort Bs[4][128][8];
    int tid = threadIdx.x;
    int wave = tid >> 6;
    int lane = tid & 63;
    int r16 = lane & 15, q = lane >> 4;
    int bm = blockIdx.x * 128;
    int bn = blockIdx.y * 128;
    int wm = (wave >> 1) * 64, wn = (wave & 1) * 64;

    f32x4 acc[4][4] = {};

    int srow = tid & 127;
    int koff0 = tid >> 7;
    int arow = bm + srow; if (arow >= M) arow = M - 1;
    const ushort* aptr = x_bf + (size_t)arow * K0PAD;
    const ushort* bptr = wt0 + (size_t)(bn + srow) * K0PAD;
    char* AsB = (char*)&As[0][0][0];
    char* BsB = (char*)&Bs[0][0][0];
    int woff = wave * 1024;

    const short8* As8 = (const short8*)&As[0][0][0];
    const short8* Bs8 = (const short8*)&Bs[0][0][0];

    for (int k0 = 0; k0 < K0PAD; k0 += 32) {
        __builtin_amdgcn_global_load_lds((const GLOBAL_AS void*)(aptr + k0 + koff0 * 8),
                                         (LDS_AS void*)(AsB + woff), 16, 0, 0);
        __builtin_amdgcn_global_load_lds((const GLOBAL_AS void*)(aptr + k0 + (koff0 + 2) * 8),
                                         (LDS_AS void*)(AsB + 4096 + woff), 16, 0, 0);
        __builtin_amdgcn_global_load_lds((const GLOBAL_AS void*)(bptr + k0 + koff0 * 8),
                                         (LDS_AS void*)(BsB + woff), 16, 0, 0);
        __builtin_amdgcn_global_load_lds((const GLOBAL_AS void*)(bptr + k0 + (koff0 + 2) * 8),
                                         (LDS_AS void*)(BsB + 4096 + woff), 16, 0, 0);
        __syncthreads();

        short8 av[4], bv[4];
#pragma unroll
        for (int mf = 0; mf < 4; ++mf)
            av[mf] = As8[q * 128 + wm + mf * 16 + r16];
#pragma unroll
        for (int nf = 0; nf < 4; ++nf)
            bv[nf] = Bs8[q * 128 + wn + nf * 16 + r16];
#pragma unroll
        for (int mf = 0; mf < 4; ++mf)
#pragma unroll
            for (int nf = 0; nf < 4; ++nf)
                acc[mf][nf] = __builtin_amdgcn_mfma_f32_16x16x32_bf16(av[mf], bv[nf], acc[mf][nf], 0, 0, 0);
        __syncthreads();
    }

#pragma unroll
    for (int mf = 0; mf < 4; ++mf) {
#pragma unroll
        for (int j = 0; j < 4; ++j) {
            int row = bm + wm + mf * 16 + q * 4 + j;
            if (row >= M) continue;
#pragma unroll
            for (int nf = 0; nf < 4; ++nf) {
                int c = bn + wn + nf * 16 + r16;
                size_t idx = (size_t)row * HID + c;
                ushort v = f2bf(fmaxf(acc[mf][nf][j] + b[c], 0.f));
                x0_bf[idx] = v;
                h_bf[idx]  = v;
            }
        }
    }
}

// -------- fused layer: phase1 gather+mix s-tile into LDS, phase2 MFMA GEMM + residual --
// s_tile swizzle: byte kb at row r stored at kb ^ ((r&7)<<4)  (bits 4-6) -> <=2-way banks
__global__ __launch_bounds__(512) void layer_fused(
        const int* __restrict__ row_ptr, const int* __restrict__ col,
        const float* __restrict__ wv, const ushort* __restrict__ h_in,
        const ushort* __restrict__ x0_bf, const ushort* __restrict__ wt,
        ushort* __restrict__ h_out, int n) {
    __shared__ ushort s_tile[128 * 256];   // 64 KB, swizzled row-major
    __shared__ ushort Bs[4 * 256 * 8];     // 16 KB
    int tid = threadIdx.x;
    int wave = tid >> 6;
    int lane = tid & 63;
    int bm = blockIdx.x * 128;

    // ---- phase 1: gather + alpha-mix ----
    {
        int f0 = lane * 4;                 // 4 features per lane
        int kb = lane * 8;                 // byte offset within row
        for (int i = 0; i < 16; ++i) {
            int r = wave * 16 + i;         // local row
            int node = bm + r;
            ushort4 res;
            if (node < n) {
                float a0 = 0.f, a1 = 0.f, a2 = 0.f, a3 = 0.f;
                int beg = row_ptr[node], end = row_ptr[node + 1];
                int e = beg;
                for (; e + 4 <= end; e += 4) {
                    int c0 = col[e], c1 = col[e + 1], c2 = col[e + 2], c3 = col[e + 3];
                    float w0 = wv[e], w1 = wv[e + 1], w2 = wv[e + 2], w3 = wv[e + 3];
                    ushort4 v0 = *reinterpret_cast<const ushort4*>(&h_in[(size_t)c0 * HID + f0]);
                    ushort4 v1 = *reinterpret_cast<const ushort4*>(&h_in[(size_t)c1 * HID + f0]);
                    ushort4 v2 = *reinterpret_cast<const ushort4*>(&h_in[(size_t)c2 * HID + f0]);
                    ushort4 v3 = *reinterpret_cast<const ushort4*>(&h_in[(size_t)c3 * HID + f0]);
                    a0 = fmaf(w0, bf2f(v0.x), a0); a1 = fmaf(w0, bf2f(v0.y), a1);
                    a2 = fmaf(w0, bf2f(v0.z), a2); a3 = fmaf(w0, bf2f(v0.w), a3);
                    a0 = fmaf(w1, bf2f(v1.x), a0); a1 = fmaf(w1, bf2f(v1.y), a1);
                    a2 = fmaf(w1, bf2f(v1.z), a2); a3 = fmaf(w1, bf2f(v1.w), a3);
                    a0 = fmaf(w2, bf2f(v2.x), a0); a1 = fmaf(w2, bf2f(v2.y), a1);
                    a2 = fmaf(w2, bf2f(v2.z), a2); a3 = fmaf(w2, bf2f(v2.w), a3);
                    a0 = fmaf(w3, bf2f(v3.x), a0); a1 = fmaf(w3, bf2f(v3.y), a1);
                    a2 = fmaf(w3, bf2f(v3.z), a2); a3 = fmaf(w3, bf2f(v3.w), a3);
                }
                for (; e < end; ++e) {
                    int c0 = col[e];
                    float w0 = wv[e];
                    ushort4 v0 = *reinterpret_cast<const ushort4*>(&h_in[(size_t)c0 * HID + f0]);
                    a0 = fmaf(w0, bf2f(v0.x), a0); a1 = fmaf(w0, bf2f(v0.y), a1);
                    a2 = fmaf(w0, bf2f(v0.z), a2); a3 = fmaf(w0, bf2f(v0.w), a3);
                }
                size_t idx = (size_t)node * HID + f0;
                ushort4 xv = *reinterpret_cast<const ushort4*>(&x0_bf[idx]);
                res.x = f2bf(0.9f * a0 + 0.1f * bf2f(xv.x));
                res.y = f2bf(0.9f * a1 + 0.1f * bf2f(xv.y));
                res.z = f2bf(0.9f * a2 + 0.1f * bf2f(xv.z));
                res.w = f2bf(0.9f * a3 + 0.1f * bf2f(xv.w));
            } else {
                res.x = 0; res.y = 0; res.z = 0; res.w = 0;
            }
            *reinterpret_cast<ushort4*>((char*)s_tile + r * 512 + (kb ^ ((r & 7) << 4))) = res;
        }
    }
    __syncthreads();

    // ---- phase 2: GEMM (s_tile @ wt) + residual relu ----
    int r16 = lane & 15, q = lane >> 4;
    int wm = (wave >> 2) * 64, wn = (wave & 3) * 64;   // 2x4 wave grid
    f32x4 acc[4][4] = {};
    char* BsB = (char*)Bs;
    const short8* Bs8 = (const short8*)Bs;

    for (int k0 = 0; k0 < HID; k0 += 32) {
        {
            int nn0 = tid & 255, kc0 = tid >> 8;
            __builtin_amdgcn_global_load_lds(
                (const GLOBAL_AS void*)(wt + (size_t)nn0 * HID + k0 + kc0 * 8),
                (LDS_AS void*)(BsB + tid * 16), 16, 0, 0);
            int flat1 = tid + 512;
            int nn1 = flat1 & 255, kc1 = flat1 >> 8;
            __builtin_amdgcn_global_load_lds(
                (const GLOBAL_AS void*)(wt + (size_t)nn1 * HID + k0 + kc1 * 8),
                (LDS_AS void*)(BsB + flat1 * 16), 16, 0, 0);
        }
        __syncthreads();

        short8 av[4], bv[4];
#pragma unroll
        for (int mf = 0; mf < 4; ++mf) {
            int row = wm + mf * 16 + r16;
            int kbyte = (2 * k0 + q * 16) ^ ((row & 7) << 4);
            av[mf] = *reinterpret_cast<const short8*>((const char*)s_tile + row * 512 + kbyte);
        }
#pragma unroll
        for (int nf = 0; nf < 4; ++nf)
            bv[nf] = Bs8[q * 256 + wn + nf * 16 + r16];
#pragma unroll
        for (int mf = 0; mf < 4; ++mf)
#pragma unroll
            for (int nf = 0; nf < 4; ++nf)
                acc[mf][nf] = __builtin_amdgcn_mfma_f32_16x16x32_bf16(av[mf], bv[nf], acc[mf][nf], 0, 0, 0);
        __syncthreads();
    }

#pragma unroll
    for (int mf = 0; mf < 4; ++mf) {
#pragma unroll
        for (int j = 0; j < 4; ++j) {
            int row = bm + wm + mf * 16 + q * 4 + j;
            if (row >= n) continue;
#pragma unroll
            for (int nf = 0; nf < 4; ++nf) {
                int c = wn + nf * 16 + r16;
                size_t idx = (size_t)row * HID + c;
                float v = fmaxf(acc[mf][nf][j] + bf2f(h_in[idx]), 0.f);
                h_out[idx] = f2bf(v);
            }
        }
    }
}

// ---------------- MFMA lin1: out = h @ lin1_w + b ----------------
__global__ __launch_bounds__(256) void lin1_mfma(
        const ushort* __restrict__ h_bf, const ushort* __restrict__ wt1,
        const float* __restrict__ b, float* __restrict__ out, int M) {
    __shared__ ushort As[4][128][8];
    __shared__ ushort Bs[4][128][8];
    int tid = threadIdx.x;
    int wave = tid >> 6;
    int lane = tid & 63;
    int r16 = lane & 15, q = lane >> 4;
    int bm = blockIdx.x * 128;
    int wm = (wave >> 1) * 64, wn = (wave & 1) * 64;

    f32x4 acc[4][4] = {};

    int srow = tid & 127;
    int koff0 = tid >> 7;
    int arow = bm + srow; if (arow >= M) arow = M - 1;
    const ushort* aptr = h_bf + (size_t)arow * HID;
    const ushort* bptr = wt1 + (size_t)srow * HID;
    char* AsB = (char*)&As[0][0][0];
    char* BsB = (char*)&Bs[0][0][0];
    int woff = wave * 1024;

    const short8* As8 = (const short8*)&As[0][0][0];
    const short8* Bs8 = (const short8*)&Bs[0][0][0];

    for (int k0 = 0; k0 < HID; k0 += 32) {
        __builtin_amdgcn_global_load_lds((const GLOBAL_AS void*)(aptr + k0 + koff0 * 8),
                                         (LDS_AS void*)(AsB + woff), 16, 0, 0);
        __builtin_amdgcn_global_load_lds((const GLOBAL_AS void*)(aptr + k0 + (koff0 + 2) * 8),
                                         (LDS_AS void*)(AsB + 4096 + woff), 16, 0, 0);
        __builtin_amdgcn_global_load_lds((const GLOBAL_AS void*)(bptr + k0 + koff0 * 8),
                                         (LDS_AS void*)(BsB + woff), 16, 0, 0);
        __builtin_amdgcn_global_load_lds((const GLOBAL_AS void*)(bptr + k0 + (koff0 + 2) * 8),
                                         (LDS_AS void*)(BsB + 4096 + woff), 16, 0, 0);
        __syncthreads();

        short8 av[4], bv[4];
#pragma unroll
        for (int mf = 0; mf < 4; ++mf)
            av[mf] = As8[q * 128 + wm + mf * 16 + r16];
#pragma unroll
        for (int nf = 0; nf < 4; ++nf)
            bv[nf] = Bs8[q * 128 + wn + nf * 16 + r16];
#pragma unroll
        for (int mf = 0; mf < 4; ++mf)
#pragma unroll
            for (int nf = 0; nf < 4; ++nf)
                acc[mf][nf] = __builtin_amdgcn_mfma_f32_16x16x32_bf16(av[mf], bv[nf], acc[mf][nf], 0, 0, 0);
        __syncthreads();
    }

#pragma unroll
    for (int mf = 0; mf < 4; ++mf) {
#pragma unroll
        for (int j = 0; j < 4; ++j) {
            int row = bm + wm + mf * 16 + q * 4 + j;
            if (row >= M) continue;
#pragma unroll
            for (int nf = 0; nf < 4; ++nf) {
                int c = wn + nf * 16 + r16;
                if (c < OUT_F)
                    out[(size_t)row * OUT_F + c] = acc[mf][nf][j] + b[c];
            }
        }
    }
}

extern "C" void kernel_launch(void* const* d_in, const int* in_sizes, int n_in,
                              void* d_out, int out_size, void* d_ws, size_t ws_size,
                              hipStream_t stream) {
    const float* x      = (const float*)d_in[0];
    const int*   ei     = (const int*)d_in[1];
    const float* ew     = (const float*)d_in[2];
    const float* lin0_w = (const float*)d_in[3];
    const float* lin0_b = (const float*)d_in[4];
    const float* W      = (const float*)d_in[5];
    const float* lin1_w = (const float*)d_in[6];
    const float* lin1_b = (const float*)d_in[7];
    float* out = (float*)d_out;

    int N = in_sizes[0] / IN_F;
    int E = in_sizes[2];
    const int* src = ei;
    const int* dst = ei + E;

    char* ws = (char*)d_ws;
    ushort* x0_bf   = (ushort*)ws; ws += (size_t)N * HID * 2;
    ushort* h_a     = (ushort*)ws; ws += (size_t)N * HID * 2;
    ushort* h_b     = (ushort*)ws; ws += (size_t)N * HID * 2;
    ushort* x_bf    = (ushort*)ws; ws += (size_t)N * K0PAD * 2;
    ushort* Wt0     = (ushort*)ws; ws += (size_t)HID * K0PAD * 2;
    ushort* Wt      = (ushort*)ws; ws += (size_t)N_LAYERS * HID * HID * 2;
    ushort* Wt1     = (ushort*)ws; ws += (size_t)128 * HID * 2;
    int*    row_ptr = (int*)ws;    ws += (size_t)(N + 1) * 4;
    int*    counts  = (int*)ws;    ws += (size_t)N * 4;
    int*    cursor  = (int*)ws;    ws += (size_t)N * 4;
    int*    bsum    = (int*)ws;    ws += (size_t)128 * 4;
    int*    col     = (int*)ws;    ws += (size_t)E * 4;
    float*  wv      = (float*)ws;  ws += (size_t)E * 4;

    int nb = (N + 1023) / 1024;

    size_t prep_tot = (size_t)N * K0PAD + HID * K0PAD
                    + (size_t)N_LAYERS * HID * HID + 128 * HID + N;
    prep_kernel<<<(int)((prep_tot + 255) / 256), 256, 0, stream>>>(
        x, lin0_w, W, lin1_w, x_bf, Wt0, Wt, Wt1, counts, N);

    hist_kernel<<<(E + 255) / 256, 256, 0, stream>>>(dst, counts, E);
    scan_phase1<<<nb, 1024, 0, stream>>>(counts, row_ptr, bsum, N);
    scan_phase2<<<1, 64, 0, stream>>>(bsum, nb);
    scan_phase3<<<nb, 1024, 0, stream>>>(row_ptr, cursor, bsum, N, nb);
    scatter_kernel<<<(E + 255) / 256, 256, 0, stream>>>(src, dst, ew, cursor, col, wv, E);

    int mblocks = (N + 127) / 128;
    lin0_mfma<<<dim3(mblocks, 2), 256, 0, stream>>>(x_bf, Wt0, lin0_b, x0_bf, h_a, N);

    // ping-pong h across layers: lin0 -> h_a; l0: a->b; l1: b->a; l2: a->b; l3: b->a
    for (int l = 0; l < N_LAYERS; ++l) {
        const ushort* hin  = (l & 1) ? h_b : h_a;
        ushort*       hout = (l & 1) ? h_a : h_b;
        layer_fused<<<mblocks, 512, 0, stream>>>(
            row_ptr, col, wv, hin, x0_bf, Wt + (size_t)l * HID * HID, hout, N);
    }

    lin1_mfma<<<mblocks, 256, 0, stream>>>(h_a, Wt1, lin1_b, out, N);
}

// Round 7
// 350.391 us; speedup vs baseline: 1.0513x; 1.0513x over previous
//
#include <hip/hip_runtime.h>
#include <math.h>

#define IN_F   50
#define HID    256
#define OUT_F  121
#define N_LAYERS 4
#define K0PAD  64

typedef __attribute__((ext_vector_type(8))) short short8;
typedef __attribute__((ext_vector_type(4))) float f32x4;

#define GLOBAL_AS __attribute__((address_space(1)))
#define LDS_AS    __attribute__((address_space(3)))

__device__ __forceinline__ ushort f2bf(float f) {
    union { float f; unsigned u; } c; c.f = f;
    unsigned u = c.u;
    u += 0x7fffu + ((u >> 16) & 1u);
    return (ushort)(u >> 16);
}
__device__ __forceinline__ float bf2f(ushort u) {
    union { unsigned u; float f; } c; c.u = ((unsigned)u) << 16;
    return c.f;
}

// ---------------- prep: all weight converts + counts zero, one kernel ----------------
// Wt layout per layer: [ts=K/32][kq=0..3][n=0..255][j=0..7], element k = ts*32+kq*8+j
// => staging source for K-step ts is CONTIGUOUS (matches LDS [kq][n][8] order).
__global__ __launch_bounds__(256) void prep_kernel(
        const float* __restrict__ x, const float* __restrict__ w0,
        const float* __restrict__ W, const float* __restrict__ w1,
        ushort* __restrict__ x_bf, ushort* __restrict__ wt0,
        ushort* __restrict__ Wt, ushort* __restrict__ wt1,
        int* __restrict__ counts, int n) {
    long long flat = (long long)blockIdx.x * 256 + threadIdx.x;
    long long r0 = (long long)n * K0PAD;
    if (flat < r0) {                       // x -> x_bf padded to K=64
        int nd = (int)(flat >> 6), k = (int)(flat & 63);
        x_bf[flat] = (k < IN_F) ? f2bf(x[(size_t)nd * IN_F + k]) : 0;
        return;
    }
    flat -= r0;
    if (flat < HID * K0PAD) {              // lin0_w transpose
        int nn = (int)(flat >> 6), k = (int)(flat & 63);
        wt0[flat] = (k < IN_F) ? f2bf(w0[(size_t)k * HID + nn]) : 0;
        return;
    }
    flat -= HID * K0PAD;
    if (flat < N_LAYERS * HID * HID) {     // W fold beta, subtile layout
        int l = (int)(flat >> 16);
        int rem = (int)(flat & 65535);
        int ts = rem >> 13;
        int kq = (rem >> 11) & 3;
        int nn = (rem >> 3) & 255;
        int j  = rem & 7;
        int k  = ts * 32 + kq * 8 + j;
        float beta = logf(0.5f / (float)(l + 1) + 1.0f);
        float v = beta * W[(size_t)l * HID * HID + (size_t)k * HID + nn];
        if (k == nn) v += 1.0f - beta;
        Wt[flat] = f2bf(v);
        return;
    }
    flat -= N_LAYERS * HID * HID;
    if (flat < 128 * HID) {                // lin1_w transpose, pad 121->128
        int nn = (int)(flat >> 8), k = (int)(flat & 255);
        wt1[flat] = (nn < OUT_F) ? f2bf(w1[(size_t)k * OUT_F + nn]) : 0;
        return;
    }
    flat -= 128 * HID;
    if (flat < n) counts[flat] = 0;
}

// ---------------- CSR build ----------------
__global__ void hist_kernel(const int* __restrict__ dst, int* __restrict__ counts, int E) {
    int e = blockIdx.x * blockDim.x + threadIdx.x;
    if (e < E) atomicAdd(&counts[dst[e]], 1);
}

__global__ void scan_phase1(const int* __restrict__ counts, int* __restrict__ row_ptr,
                            int* __restrict__ bsum, int n) {
    __shared__ int sd[1024];
    int t = threadIdx.x;
    int i = blockIdx.x * 1024 + t;
    int v = (i < n) ? counts[i] : 0;
    sd[t] = v;
    __syncthreads();
    for (int off = 1; off < 1024; off <<= 1) {
        int tmp = (t >= off) ? sd[t - off] : 0;
        __syncthreads();
        sd[t] += tmp;
        __syncthreads();
    }
    if (i < n) row_ptr[i] = sd[t] - v;
    if (t == 1023) bsum[blockIdx.x] = sd[1023];
}

__global__ void scan_phase2(int* __restrict__ bsum, int nb) {
    __shared__ int sd[64];
    int t = threadIdx.x;
    int v = (t < nb) ? bsum[t] : 0;
    sd[t] = v;
    __syncthreads();
    for (int off = 1; off < 64; off <<= 1) {
        int tmp = (t >= off) ? sd[t - off] : 0;
        __syncthreads();
        sd[t] += tmp;
        __syncthreads();
    }
    if (t < nb) bsum[t] = sd[t] - v;
    if (t == nb - 1) bsum[nb] = sd[t];
}

__global__ void scan_phase3(int* __restrict__ row_ptr, int* __restrict__ cursor,
                            const int* __restrict__ bsum, int n, int nb) {
    int i = blockIdx.x * 1024 + threadIdx.x;
    if (i < n) {
        int v = row_ptr[i] + bsum[blockIdx.x];
        row_ptr[i] = v;
        cursor[i]  = v;
    }
    if (i == n - 1) row_ptr[n] = bsum[nb];
}

__global__ void scatter_kernel(const int* __restrict__ src, const int* __restrict__ dst,
                               const float* __restrict__ ew, int* __restrict__ cursor,
                               int* __restrict__ col, float* __restrict__ wv, int E) {
    int e = blockIdx.x * blockDim.x + threadIdx.x;
    if (e < E) {
        int d = dst[e];
        int pos = atomicAdd(&cursor[d], 1);
        col[pos] = src[e];
        wv[pos] = ew[e];
    }
}

// ---------------- lin0 MFMA: x0 = relu(x_bf @ Wt0^T + b), K=64 ----------------
__global__ __launch_bounds__(256) void lin0_mfma(
        const ushort* __restrict__ x_bf, const ushort* __restrict__ wt0,
        const float* __restrict__ b, ushort* __restrict__ x0_bf,
        ushort* __restrict__ h_bf, int M) {
    __shared__ ushort As[4][128][8];
    __shared__ ushort Bs[4][128][8];
    int tid = threadIdx.x;
    int wave = tid >> 6;
    int lane = tid & 63;
    int r16 = lane & 15, q = lane >> 4;
    int bm = blockIdx.x * 128;
    int bn = blockIdx.y * 128;
    int wm = (wave >> 1) * 64, wn = (wave & 1) * 64;

    f32x4 acc[4][4] = {};

    int srow = tid & 127;
    int koff0 = tid >> 7;
    int arow = bm + srow; if (arow >= M) arow = M - 1;
    const ushort* aptr = x_bf + (size_t)arow * K0PAD;
    const ushort* bptr = wt0 + (size_t)(bn + srow) * K0PAD;
    char* AsB = (char*)&As[0][0][0];
    char* BsB = (char*)&Bs[0][0][0];
    int woff = wave * 1024;

    const short8* As8 = (const short8*)&As[0][0][0];
    const short8* Bs8 = (const short8*)&Bs[0][0][0];

    for (int k0 = 0; k0 < K0PAD; k0 += 32) {
        __builtin_amdgcn_global_load_lds((const GLOBAL_AS void*)(aptr + k0 + koff0 * 8),
                                         (LDS_AS void*)(AsB + woff), 16, 0, 0);
        __builtin_amdgcn_global_load_lds((const GLOBAL_AS void*)(aptr + k0 + (koff0 + 2) * 8),
                                         (LDS_AS void*)(AsB + 4096 + woff), 16, 0, 0);
        __builtin_amdgcn_global_load_lds((const GLOBAL_AS void*)(bptr + k0 + koff0 * 8),
                                         (LDS_AS void*)(BsB + woff), 16, 0, 0);
        __builtin_amdgcn_global_load_lds((const GLOBAL_AS void*)(bptr + k0 + (koff0 + 2) * 8),
                                         (LDS_AS void*)(BsB + 4096 + woff), 16, 0, 0);
        __syncthreads();

        short8 av[4], bv[4];
#pragma unroll
        for (int mf = 0; mf < 4; ++mf)
            av[mf] = As8[q * 128 + wm + mf * 16 + r16];
#pragma unroll
        for (int nf = 0; nf < 4; ++nf)
            bv[nf] = Bs8[q * 128 + wn + nf * 16 + r16];
#pragma unroll
        for (int mf = 0; mf < 4; ++mf)
#pragma unroll
            for (int nf = 0; nf < 4; ++nf)
                acc[mf][nf] = __builtin_amdgcn_mfma_f32_16x16x32_bf16(av[mf], bv[nf], acc[mf][nf], 0, 0, 0);
        __syncthreads();
    }

#pragma unroll
    for (int mf = 0; mf < 4; ++mf) {
#pragma unroll
        for (int j = 0; j < 4; ++j) {
            int row = bm + wm + mf * 16 + q * 4 + j;
            if (row >= M) continue;
#pragma unroll
            for (int nf = 0; nf < 4; ++nf) {
                int c = bn + wn + nf * 16 + r16;
                size_t idx = (size_t)row * HID + c;
                ushort v = f2bf(fmaxf(acc[mf][nf][j] + b[c], 0.f));
                x0_bf[idx] = v;
                h_bf[idx]  = v;
            }
        }
    }
}

// -------- fused layer, BM=64 x BN=256: phase1 gather s-tile to LDS, phase2 MFMA --------
// LDS: s_tile 32KB (swizzled) + Bs 16KB = 48KB -> 3 blocks/CU.
__global__ __launch_bounds__(512) void layer_fused(
        const int* __restrict__ row_ptr, const int* __restrict__ col,
        const float* __restrict__ wv, const ushort* __restrict__ h_in,
        const ushort* __restrict__ x0_bf, const ushort* __restrict__ wt,
        ushort* __restrict__ h_out, int n) {
    __shared__ ushort s_tile[64 * 256];    // 32 KB, swizzled rows of 512 B
    __shared__ ushort Bs[4 * 256 * 8];     // 16 KB
    int tid = threadIdx.x;
    int wave = tid >> 6;
    int lane = tid & 63;
    int bm = blockIdx.x * 64;

    // ---- phase 1: gather + alpha-mix, 8 rows per wave ----
    {
        int f0 = lane * 4;
        int kb = lane * 8;                 // byte offset within 512 B row
        for (int i = 0; i < 8; ++i) {
            int r = wave * 8 + i;
            int node = bm + r;
            ushort4 res;
            if (node < n) {
                float a0 = 0.f, a1 = 0.f, a2 = 0.f, a3 = 0.f;
                int beg = row_ptr[node], end = row_ptr[node + 1];
                int e = beg;
                for (; e + 4 <= end; e += 4) {
                    int c0 = col[e], c1 = col[e + 1], c2 = col[e + 2], c3 = col[e + 3];
                    float w0 = wv[e], w1 = wv[e + 1], w2 = wv[e + 2], w3 = wv[e + 3];
                    ushort4 v0 = *reinterpret_cast<const ushort4*>(&h_in[(size_t)c0 * HID + f0]);
                    ushort4 v1 = *reinterpret_cast<const ushort4*>(&h_in[(size_t)c1 * HID + f0]);
                    ushort4 v2 = *reinterpret_cast<const ushort4*>(&h_in[(size_t)c2 * HID + f0]);
                    ushort4 v3 = *reinterpret_cast<const ushort4*>(&h_in[(size_t)c3 * HID + f0]);
                    a0 = fmaf(w0, bf2f(v0.x), a0); a1 = fmaf(w0, bf2f(v0.y), a1);
                    a2 = fmaf(w0, bf2f(v0.z), a2); a3 = fmaf(w0, bf2f(v0.w), a3);
                    a0 = fmaf(w1, bf2f(v1.x), a0); a1 = fmaf(w1, bf2f(v1.y), a1);
                    a2 = fmaf(w1, bf2f(v1.z), a2); a3 = fmaf(w1, bf2f(v1.w), a3);
                    a0 = fmaf(w2, bf2f(v2.x), a0); a1 = fmaf(w2, bf2f(v2.y), a1);
                    a2 = fmaf(w2, bf2f(v2.z), a2); a3 = fmaf(w2, bf2f(v2.w), a3);
                    a0 = fmaf(w3, bf2f(v3.x), a0); a1 = fmaf(w3, bf2f(v3.y), a1);
                    a2 = fmaf(w3, bf2f(v3.z), a2); a3 = fmaf(w3, bf2f(v3.w), a3);
                }
                for (; e < end; ++e) {
                    int c0 = col[e];
                    float w0 = wv[e];
                    ushort4 v0 = *reinterpret_cast<const ushort4*>(&h_in[(size_t)c0 * HID + f0]);
                    a0 = fmaf(w0, bf2f(v0.x), a0); a1 = fmaf(w0, bf2f(v0.y), a1);
                    a2 = fmaf(w0, bf2f(v0.z), a2); a3 = fmaf(w0, bf2f(v0.w), a3);
                }
                size_t idx = (size_t)node * HID + f0;
                ushort4 xv = *reinterpret_cast<const ushort4*>(&x0_bf[idx]);
                res.x = f2bf(0.9f * a0 + 0.1f * bf2f(xv.x));
                res.y = f2bf(0.9f * a1 + 0.1f * bf2f(xv.y));
                res.z = f2bf(0.9f * a2 + 0.1f * bf2f(xv.z));
                res.w = f2bf(0.9f * a3 + 0.1f * bf2f(xv.w));
            } else {
                res.x = 0; res.y = 0; res.z = 0; res.w = 0;
            }
            *reinterpret_cast<ushort4*>((char*)s_tile + r * 512 + (kb ^ ((r & 7) << 4))) = res;
        }
    }
    __syncthreads();

    // ---- phase 2: GEMM (s_tile[64x256] @ wt[256x256]) + residual relu ----
    int r16 = lane & 15, q = lane >> 4;
    int wm = (wave >> 2) * 32, wn = (wave & 3) * 64;   // 2x4 wave grid
    f32x4 acc[2][4] = {};
    char* BsB = (char*)Bs;
    const short8* Bs8 = (const short8*)Bs;

    for (int ts = 0; ts < 8; ++ts) {
        // stage Wt K-step ts: contiguous source (pre-arranged), linear LDS dest
        __builtin_amdgcn_global_load_lds(
            (const GLOBAL_AS void*)(wt + (size_t)ts * 8192 + tid * 8),
            (LDS_AS void*)(BsB + tid * 16), 16, 0, 0);
        __builtin_amdgcn_global_load_lds(
            (const GLOBAL_AS void*)(wt + (size_t)ts * 8192 + (tid + 512) * 8),
            (LDS_AS void*)(BsB + (tid + 512) * 16), 16, 0, 0);
        __syncthreads();

        short8 av[2], bv[4];
#pragma unroll
        for (int mf = 0; mf < 2; ++mf) {
            int row = wm + mf * 16 + r16;
            int kbyte = (64 * ts + q * 16) ^ ((row & 7) << 4);
            av[mf] = *reinterpret_cast<const short8*>((const char*)s_tile + row * 512 + kbyte);
        }
#pragma unroll
        for (int nf = 0; nf < 4; ++nf)
            bv[nf] = Bs8[q * 256 + wn + nf * 16 + r16];
#pragma unroll
        for (int mf = 0; mf < 2; ++mf)
#pragma unroll
            for (int nf = 0; nf < 4; ++nf)
                acc[mf][nf] = __builtin_amdgcn_mfma_f32_16x16x32_bf16(av[mf], bv[nf], acc[mf][nf], 0, 0, 0);
        __syncthreads();
    }

#pragma unroll
    for (int mf = 0; mf < 2; ++mf) {
#pragma unroll
        for (int j = 0; j < 4; ++j) {
            int row = bm + wm + mf * 16 + q * 4 + j;
            if (row >= n) continue;
#pragma unroll
            for (int nf = 0; nf < 4; ++nf) {
                int c = wn + nf * 16 + r16;
                size_t idx = (size_t)row * HID + c;
                float v = fmaxf(acc[mf][nf][j] + bf2f(h_in[idx]), 0.f);
                h_out[idx] = f2bf(v);
            }
        }
    }
}

// ---------------- MFMA lin1: out = h @ lin1_w + b ----------------
__global__ __launch_bounds__(256) void lin1_mfma(
        const ushort* __restrict__ h_bf, const ushort* __restrict__ wt1,
        const float* __restrict__ b, float* __restrict__ out, int M) {
    __shared__ ushort As[4][128][8];
    __shared__ ushort Bs[4][128][8];
    int tid = threadIdx.x;
    int wave = tid >> 6;
    int lane = tid & 63;
    int r16 = lane & 15, q = lane >> 4;
    int bm = blockIdx.x * 128;
    int wm = (wave >> 1) * 64, wn = (wave & 1) * 64;

    f32x4 acc[4][4] = {};

    int srow = tid & 127;
    int koff0 = tid >> 7;
    int arow = bm + srow; if (arow >= M) arow = M - 1;
    const ushort* aptr = h_bf + (size_t)arow * HID;
    const ushort* bptr = wt1 + (size_t)srow * HID;
    char* AsB = (char*)&As[0][0][0];
    char* BsB = (char*)&Bs[0][0][0];
    int woff = wave * 1024;

    const short8* As8 = (const short8*)&As[0][0][0];
    const short8* Bs8 = (const short8*)&Bs[0][0][0];

    for (int k0 = 0; k0 < HID; k0 += 32) {
        __builtin_amdgcn_global_load_lds((const GLOBAL_AS void*)(aptr + k0 + koff0 * 8),
                                         (LDS_AS void*)(AsB + woff), 16, 0, 0);
        __builtin_amdgcn_global_load_lds((const GLOBAL_AS void*)(aptr + k0 + (koff0 + 2) * 8),
                                         (LDS_AS void*)(AsB + 4096 + woff), 16, 0, 0);
        __builtin_amdgcn_global_load_lds((const GLOBAL_AS void*)(bptr + k0 + koff0 * 8),
                                         (LDS_AS void*)(BsB + woff), 16, 0, 0);
        __builtin_amdgcn_global_load_lds((const GLOBAL_AS void*)(bptr + k0 + (koff0 + 2) * 8),
                                         (LDS_AS void*)(BsB + 4096 + woff), 16, 0, 0);
        __syncthreads();

        short8 av[4], bv[4];
#pragma unroll
        for (int mf = 0; mf < 4; ++mf)
            av[mf] = As8[q * 128 + wm + mf * 16 + r16];
#pragma unroll
        for (int nf = 0; nf < 4; ++nf)
            bv[nf] = Bs8[q * 128 + wn + nf * 16 + r16];
#pragma unroll
        for (int mf = 0; mf < 4; ++mf)
#pragma unroll
            for (int nf = 0; nf < 4; ++nf)
                acc[mf][nf] = __builtin_amdgcn_mfma_f32_16x16x32_bf16(av[mf], bv[nf], acc[mf][nf], 0, 0, 0);
        __syncthreads();
    }

#pragma unroll
    for (int mf = 0; mf < 4; ++mf) {
#pragma unroll
        for (int j = 0; j < 4; ++j) {
            int row = bm + wm + mf * 16 + q * 4 + j;
            if (row >= M) continue;
#pragma unroll
            for (int nf = 0; nf < 4; ++nf) {
                int c = wn + nf * 16 + r16;
                if (c < OUT_F)
                    out[(size_t)row * OUT_F + c] = acc[mf][nf][j] + b[c];
            }
        }
    }
}

extern "C" void kernel_launch(void* const* d_in, const int* in_sizes, int n_in,
                              void* d_out, int out_size, void* d_ws, size_t ws_size,
                              hipStream_t stream) {
    const float* x      = (const float*)d_in[0];
    const int*   ei     = (const int*)d_in[1];
    const float* ew     = (const float*)d_in[2];
    const float* lin0_w = (const float*)d_in[3];
    const float* lin0_b = (const float*)d_in[4];
    const float* W      = (const float*)d_in[5];
    const float* lin1_w = (const float*)d_in[6];
    const float* lin1_b = (const float*)d_in[7];
    float* out = (float*)d_out;

    int N = in_sizes[0] / IN_F;
    int E = in_sizes[2];
    const int* src = ei;
    const int* dst = ei + E;

    char* ws = (char*)d_ws;
    ushort* x0_bf   = (ushort*)ws; ws += (size_t)N * HID * 2;
    ushort* h_a     = (ushort*)ws; ws += (size_t)N * HID * 2;
    ushort* h_b     = (ushort*)ws; ws += (size_t)N * HID * 2;
    ushort* x_bf    = (ushort*)ws; ws += (size_t)N * K0PAD * 2;
    ushort* Wt0     = (ushort*)ws; ws += (size_t)HID * K0PAD * 2;
    ushort* Wt      = (ushort*)ws; ws += (size_t)N_LAYERS * HID * HID * 2;
    ushort* Wt1     = (ushort*)ws; ws += (size_t)128 * HID * 2;
    int*    row_ptr = (int*)ws;    ws += (size_t)(N + 1) * 4;
    int*    counts  = (int*)ws;    ws += (size_t)N * 4;
    int*    cursor  = (int*)ws;    ws += (size_t)N * 4;
    int*    bsum    = (int*)ws;    ws += (size_t)128 * 4;
    int*    col     = (int*)ws;    ws += (size_t)E * 4;
    float*  wv      = (float*)ws;  ws += (size_t)E * 4;

    int nb = (N + 1023) / 1024;

    size_t prep_tot = (size_t)N * K0PAD + HID * K0PAD
                    + (size_t)N_LAYERS * HID * HID + 128 * HID + N;
    prep_kernel<<<(int)((prep_tot + 255) / 256), 256, 0, stream>>>(
        x, lin0_w, W, lin1_w, x_bf, Wt0, Wt, Wt1, counts, N);

    hist_kernel<<<(E + 255) / 256, 256, 0, stream>>>(dst, counts, E);
    scan_phase1<<<nb, 1024, 0, stream>>>(counts, row_ptr, bsum, N);
    scan_phase2<<<1, 64, 0, stream>>>(bsum, nb);
    scan_phase3<<<nb, 1024, 0, stream>>>(row_ptr, cursor, bsum, N, nb);
    scatter_kernel<<<(E + 255) / 256, 256, 0, stream>>>(src, dst, ew, cursor, col, wv, E);

    int mblocks128 = (N + 127) / 128;
    lin0_mfma<<<dim3(mblocks128, 2), 256, 0, stream>>>(x_bf, Wt0, lin0_b, x0_bf, h_a, N);

    // ping-pong h: lin0 -> h_a; l0: a->b; l1: b->a; l2: a->b; l3: b->a
    int mblocks64 = (N + 63) / 64;
    for (int l = 0; l < N_LAYERS; ++l) {
        const ushort* hin  = (l & 1) ? h_b : h_a;
        ushort*       hout = (l & 1) ? h_a : h_b;
        layer_fused<<<mblocks64, 512, 0, stream>>>(
            row_ptr, col, wv, hin, x0_bf, Wt + (size_t)l * HID * HID, hout, N);
    }

    lin1_mfma<<<mblocks128, 256, 0, stream>>>(h_a, Wt1, lin1_b, out, N);
}